// Round 4
// baseline (388.118 us; speedup 1.0000x reference)
//
#include <hip/hip_runtime.h>

// B=2,H=16,S=2048,D=64 attention, no 1/sqrt(d) scale, fp32 in/out.
// Round 12 RESUBMIT (R12 bench died to container-acquire infra failure, no
// kernel verdict). Latency-bound diagnosis (R11: -16pts VALU, -7.3M
// conflicts, wall UNCHANGED; all pipes <30%) -> raise residency + shorten
// per-iter chain:
//  - V global map reverted to R9 (contiguous 256B segments; R11's scatter
//    cost ~4us). Returning V-write LDS conflicts are proven off-critical.
//  - PV fused into the np loop (process 32 keys at a time): P written and
//    consumed immediately -> Pbs 16KB->8KB (row-pair packing, same XOR
//    swizzle), and np1 QK overlaps np0 PV in the scheduler.
//  - LDS 24KB + __launch_bounds__(256,6) + 3-way key split (grid 1536 =
//    6 blocks/CU exactly) -> 24 waves/CU vs 16. Regs at the 80-total cap.
// Carries: 32-row waves x 4, S^T QK orientation, fp16 QK / bf16 PV, XOR
// swizzles, reg-prefetch pipeline, XCD head grouping, exp2/log2e, f32 lp,
// setprio around MFMA clusters.

typedef __bf16    bf16_t;
typedef _Float16  f16_t;
typedef __bf16    bf16x8 __attribute__((ext_vector_type(8)));
typedef _Float16  f16x8  __attribute__((ext_vector_type(8)));
typedef float     f32x4  __attribute__((ext_vector_type(4)));

constexpr int S  = 2048;
constexpr int Dh = 64;
constexpr int KT = 64;
constexpr int QT = 128;
constexpr float LOG2E = 1.44269504088896340736f;

// XOR swizzle on rows of 64 elems (2B each): 16B chunk idx ^= (row&7).
__device__ __forceinline__ int sw(int row, int col) {
    return row * 64 + ((((col >> 3) ^ (row & 7)) << 3) | (col & 7));
}

// P buffer swizzle: rows paired into 64 x 64-elem rows (128B, full 32 banks),
// then the same 16B-chunk XOR. row in [0,128), k in [0,32).
__device__ __forceinline__ int swp(int row, int k) {
    return sw(row >> 1, (row & 1) * 32 + k);
}

template<int SN>
__global__ __launch_bounds__(256, 6)
void attn_kernel(const float* __restrict__ Qg,
                 const float* __restrict__ Kg,
                 const float* __restrict__ Vg,
                 float* __restrict__ Og,
                 float* __restrict__ Opart,
                 float* __restrict__ lpart)
{
    __shared__ alignas(16) f16_t  Khs[KT * Dh];   // K   [key][d]  fp16 (8 KB)
    __shared__ alignas(16) bf16_t Vts[Dh * KT];   // V^T [d][key]  bf16 (8 KB)
    __shared__ alignas(16) bf16_t Pbs[64 * 64];   // P   row-paired (8 KB)

    const int tid  = threadIdx.x;
    const int lane = tid & 63;
    const int wv   = tid >> 6;       // wave 0..3
    const int l15  = lane & 15;
    const int qd   = lane >> 4;      // quad 0..3
    const int wb   = wv * 32;        // wave's 32-row base in the 128-row tile

    const int bx   = blockIdx.x;
    const int head = bx & 31;                    // XCD grouping
    const int r5   = bx >> 5;
    const int qt   = r5 / SN;                    // 0..15
    const int half = r5 % SN;
    const int tile = head * 16 + qt;             // flat output tile id
    const int ch0  = (SN == 3) ? half * 11 : half * 16;
    const int nch  = (SN == 3) ? (half == 2 ? 10 : 11) : (SN == 2 ? 16 : 32);

    const float* Qp = Qg + (size_t)tile * QT * Dh;
    const float* Kp = Kg + (size_t)head * S * Dh;
    const float* Vp = Vg + (size_t)head * S * Dh;

    // staging address components (constant per thread) — R9 map (coalesced)
    const int skey = tid >> 4;          // K staging: key row
    const int sc4  = (tid & 15) * 4;    // K staging: 4-elem col
    const int vkb  = (tid >> 4) * 4;    // V staging: 4 consecutive keys
    const int vc4  = (tid & 15) * 4;    // V staging: 4 consecutive d

    // ---- Q fragments (B-frag), 2 subtiles x 2 k-steps; log2(e) folded ----
    f16x8 qf[2][2];
    #pragma unroll
    for (int sub = 0; sub < 2; ++sub) {
        const float* qrow = Qp + (size_t)(wb + sub * 16 + l15) * Dh;
        #pragma unroll
        for (int ks = 0; ks < 2; ++ks) {
            const float* p = qrow + ks * 32 + qd * 8;
            const float4 a = *(const float4*)(p);
            const float4 b = *(const float4*)(p + 4);
            const float xs[8] = {a.x, a.y, a.z, a.w, b.x, b.y, b.z, b.w};
            #pragma unroll
            for (int j = 0; j < 8; ++j) qf[sub][ks][j] = (f16_t)(xs[j] * LOG2E);
        }
    }

    f32x4 oa[2][4];      // O acc: [subtile][4 d-tiles of 16]
    float lp[2];         // row-sum partial per subtile (lane's q-row = l15)
    #pragma unroll
    for (int s2 = 0; s2 < 2; ++s2) {
        lp[s2] = 0.f;
        #pragma unroll
        for (int t = 0; t < 4; ++t) oa[s2][t] = (f32x4){0.f, 0.f, 0.f, 0.f};
    }

    // ---- prefetch first chunk into registers ----
    float4 kbuf[4], vbuf[4];
    {
        const float* Kc = Kp + (size_t)ch0 * KT * Dh;
        const float* Vc = Vp + (size_t)ch0 * KT * Dh;
        #pragma unroll
        for (int it = 0; it < 4; ++it)
            kbuf[it] = *(const float4*)(Kc + (size_t)(it * 16 + skey) * Dh + sc4);
        #pragma unroll
        for (int i = 0; i < 4; ++i)
            vbuf[i] = *(const float4*)(Vc + (size_t)(vkb + i) * Dh + vc4);
    }

    #pragma unroll 1
    for (int ci = 0; ci < nch; ++ci) {
        __syncthreads();   // prior iter done reading Khs/Vts

        // ---- write staged registers -> LDS (cvt off the load path) ----
        #pragma unroll
        for (int it = 0; it < 4; ++it) {
            const float xs[4] = {kbuf[it].x, kbuf[it].y, kbuf[it].z, kbuf[it].w};
            union { f16_t h[4]; uint2 u; } ph;
            #pragma unroll
            for (int j = 0; j < 4; ++j) ph.h[j] = (f16_t)xs[j];
            *(uint2*)&Khs[sw(it * 16 + skey, sc4)] = ph.u;
        }
        {
            const float rs[4][4] = {{vbuf[0].x, vbuf[1].x, vbuf[2].x, vbuf[3].x},
                                    {vbuf[0].y, vbuf[1].y, vbuf[2].y, vbuf[3].y},
                                    {vbuf[0].z, vbuf[1].z, vbuf[2].z, vbuf[3].z},
                                    {vbuf[0].w, vbuf[1].w, vbuf[2].w, vbuf[3].w}};
            #pragma unroll
            for (int i = 0; i < 4; ++i) {
                union { bf16_t h[4]; uint2 u; } pv;
                #pragma unroll
                for (int j = 0; j < 4; ++j) pv.h[j] = (bf16_t)rs[i][j];
                *(uint2*)&Vts[sw(vc4 + i, vkb)] = pv.u;
            }
        }
        __syncthreads();

        // ---- issue global loads for next chunk (consumed next iteration) ----
        if (ci + 1 < nch) {
            const float* Kc = Kp + (size_t)(ch0 + ci + 1) * KT * Dh;
            const float* Vc = Vp + (size_t)(ch0 + ci + 1) * KT * Dh;
            #pragma unroll
            for (int it = 0; it < 4; ++it)
                kbuf[it] = *(const float4*)(Kc + (size_t)(it * 16 + skey) * Dh + sc4);
            #pragma unroll
            for (int i = 0; i < 4; ++i)
                vbuf[i] = *(const float4*)(Vc + (size_t)(vkb + i) * Dh + vc4);
        }

        // ---- fused per-np: QK (32 keys) -> exp/P -> PV(ks=np) ----
        #pragma unroll
        for (int np = 0; np < 2; ++np) {
            f32x4 st[2][2];   // [sub][nt within pair]
            #pragma unroll
            for (int s2 = 0; s2 < 2; ++s2)
                #pragma unroll
                for (int t = 0; t < 2; ++t) st[s2][t] = (f32x4){0.f, 0.f, 0.f, 0.f};
            __builtin_amdgcn_s_setprio(1);
            #pragma unroll
            for (int ks = 0; ks < 2; ++ks) {
                const int co = ks * 32 + qd * 8;
                const f16x8 ak0 = *(const f16x8*)&Khs[sw((np * 2 + 0) * 16 + l15, co)];
                const f16x8 ak1 = *(const f16x8*)&Khs[sw((np * 2 + 1) * 16 + l15, co)];
                #pragma unroll
                for (int s2 = 0; s2 < 2; ++s2) {
                    st[s2][0] = __builtin_amdgcn_mfma_f32_16x16x32_f16(ak0, qf[s2][ks], st[s2][0], 0, 0, 0);
                    st[s2][1] = __builtin_amdgcn_mfma_f32_16x16x32_f16(ak1, qf[s2][ks], st[s2][1], 0, 0, 0);
                }
            }
            __builtin_amdgcn_s_setprio(0);
            // p = 2^s; store this np's 32 keys into the 8KB P buffer.
            // Same-wave DS ordering makes the np0-read -> np1-write reuse safe.
            #pragma unroll
            for (int s2 = 0; s2 < 2; ++s2) {
                #pragma unroll
                for (int t = 0; t < 2; ++t) {
                    union { bf16_t h[4]; uint2 u; } pb;
                    #pragma unroll
                    for (int r = 0; r < 4; ++r) {
                        const float e = __builtin_amdgcn_exp2f(st[s2][t][r]);
                        lp[s2] += e;
                        pb.h[r] = (bf16_t)e;
                    }
                    *(uint2*)&Pbs[swp(wb + s2 * 16 + l15, t * 16 + qd * 4)] = pb.u;
                }
            }
            // PV for ks=np (vb shared across subtiles)
            const int co = np * 32 + qd * 8;
            const bf16x8 pa0 = *(const bf16x8*)&Pbs[swp(wb + l15,      qd * 8)];
            const bf16x8 pa1 = *(const bf16x8*)&Pbs[swp(wb + 16 + l15, qd * 8)];
            __builtin_amdgcn_s_setprio(1);
            #pragma unroll
            for (int dt = 0; dt < 4; ++dt) {
                const bf16x8 vb = *(const bf16x8*)&Vts[sw(dt * 16 + l15, co)];
                oa[0][dt] = __builtin_amdgcn_mfma_f32_16x16x32_bf16(pa0, vb, oa[0][dt], 0, 0, 0);
                oa[1][dt] = __builtin_amdgcn_mfma_f32_16x16x32_bf16(pa1, vb, oa[1][dt], 0, 0, 0);
            }
            __builtin_amdgcn_s_setprio(0);
        }
    }

    // ---- reduce row sums (lane's lp covers q-row=l15; reduce across quads) ----
    #pragma unroll
    for (int s2 = 0; s2 < 2; ++s2) {
        lp[s2] += __shfl_xor(lp[s2], 16, 64);
        lp[s2] += __shfl_xor(lp[s2], 32, 64);
    }

    if (SN > 1) {
        float* Po = Opart + (size_t)(tile * SN + half) * (QT * Dh);
        float* lq = lpart + (size_t)(tile * SN + half) * QT;
        #pragma unroll
        for (int s2 = 0; s2 < 2; ++s2) {
            if (qd == 0) lq[wb + s2 * 16 + l15] = lp[s2];
            #pragma unroll
            for (int r = 0; r < 4; ++r) {
                const int row = wb + s2 * 16 + qd * 4 + r;
                #pragma unroll
                for (int dt = 0; dt < 4; ++dt)
                    Po[(size_t)row * Dh + dt * 16 + l15] = oa[s2][dt][r];
            }
        }
    } else {
        float* Op = Og + (size_t)tile * QT * Dh;
        #pragma unroll
        for (int s2 = 0; s2 < 2; ++s2) {
            #pragma unroll
            for (int r = 0; r < 4; ++r) {
                const float inv = 1.0f / __shfl(lp[s2], qd * 4 + r, 64);
                const int row = wb + s2 * 16 + qd * 4 + r;
                #pragma unroll
                for (int dt = 0; dt < 4; ++dt)
                    Op[(size_t)row * Dh + dt * 16 + l15] = oa[s2][dt][r] * inv;
            }
        }
    }
}

// O = sum(Oi) / sum(li); one thread per float4 of output.
template<int SN>
__global__ __launch_bounds__(256)
void combine_kernel(const float* __restrict__ Opart,
                    const float* __restrict__ lpart,
                    float* __restrict__ Og)
{
    const int i  = blockIdx.x * 256 + threadIdx.x;   // float4 index
    const int q  = i >> 11;                          // tile 0..511 (2048 f4/tile)
    const int rw = (i >> 4) & 127;                   // row within tile
    const size_t e = (size_t)(i & 2047) * 4;
    float4 acc = {0.f, 0.f, 0.f, 0.f};
    float  l   = 0.f;
    #pragma unroll
    for (int h = 0; h < SN; ++h) {
        const float4 a = *(const float4*)(Opart + (size_t)(q * SN + h) * (QT * Dh) + e);
        l += lpart[(size_t)(q * SN + h) * QT + rw];
        acc.x += a.x; acc.y += a.y; acc.z += a.z; acc.w += a.w;
    }
    const float inv = 1.0f / l;
    float4 o;
    o.x = acc.x * inv; o.y = acc.y * inv; o.z = acc.z * inv; o.w = acc.w * inv;
    *(float4*)(Og + (size_t)i * 4) = o;
}

extern "C" void kernel_launch(void* const* d_in, const int* in_sizes, int n_in,
                              void* d_out, int out_size, void* d_ws, size_t ws_size,
                              hipStream_t stream)
{
    const float* Q = (const float*)d_in[0];
    const float* K = (const float*)d_in[1];
    const float* V = (const float*)d_in[2];
    float*       O = (float*)d_out;

    constexpr size_t TILE_O = (size_t)QT * Dh;                 // floats per tile
    constexpr size_t NEED3  = (512ull * 3 * (TILE_O + QT)) * sizeof(float); // ~51.1MB
    constexpr size_t NEED2  = (512ull * 2 * (TILE_O + QT)) * sizeof(float); // ~34.1MB
    const int n4 = (int)(512 * TILE_O / 4);                    // output float4 count

    if (ws_size >= NEED3) {
        // 3-way key split: grid 1536 = 6 blocks/CU exactly
        float* Opart = (float*)d_ws;
        float* lpart = Opart + 512ull * 3 * TILE_O;
        attn_kernel<3><<<dim3(1536), dim3(256), 0, stream>>>(
            Q, K, V, nullptr, Opart, lpart);
        combine_kernel<3><<<dim3(n4 / 256), dim3(256), 0, stream>>>(Opart, lpart, O);
    } else if (ws_size >= NEED2) {
        float* Opart = (float*)d_ws;
        float* lpart = Opart + 512ull * 2 * TILE_O;
        attn_kernel<2><<<dim3(1024), dim3(256), 0, stream>>>(
            Q, K, V, nullptr, Opart, lpart);
        combine_kernel<2><<<dim3(n4 / 256), dim3(256), 0, stream>>>(Opart, lpart, O);
    } else {
        attn_kernel<1><<<dim3(512), dim3(256), 0, stream>>>(
            Q, K, V, O, nullptr, nullptr);
    }
}

// Round 5
// 143.417 us; speedup vs baseline: 2.7062x; 2.7062x over previous
//
#include <hip/hip_runtime.h>

// B=2,H=16,S=2048,D=64 attention, no 1/sqrt(d) scale, fp32 in/out.
// Round 13: R12 post-mortem — the (256,6) register cap caused massive spill
// (VGPR 40, FETCH 514MB, WRITE 714MB of scratch traffic, 4x wall). Keep
// R12's good parts, drop the cap:
//  - __launch_bounds__(256,4): spill-free allocation (R11-verified ~64-80
//    regs). Residency now set by ACTUAL usage: 24KB LDS -> 6 blocks/CU,
//    grid 1536 -> 6 blocks/CU available (vs R11's grid-limited 4).
//  - PV fused into np loop (Pbs 8KB, LDS 24KB total), 3-way key split.
// Carries: 32-row waves x 4, S^T QK orientation, fp16 QK / bf16 PV, XOR
// swizzles, R9 coalesced staging maps, reg-prefetch pipeline, XCD head
// grouping, exp2/log2e, f32 lp, setprio around MFMA clusters.

typedef __bf16    bf16_t;
typedef _Float16  f16_t;
typedef __bf16    bf16x8 __attribute__((ext_vector_type(8)));
typedef _Float16  f16x8  __attribute__((ext_vector_type(8)));
typedef float     f32x4  __attribute__((ext_vector_type(4)));

constexpr int S  = 2048;
constexpr int Dh = 64;
constexpr int KT = 64;
constexpr int QT = 128;
constexpr float LOG2E = 1.44269504088896340736f;

// XOR swizzle on rows of 64 elems (2B each): 16B chunk idx ^= (row&7).
__device__ __forceinline__ int sw(int row, int col) {
    return row * 64 + ((((col >> 3) ^ (row & 7)) << 3) | (col & 7));
}

// P buffer swizzle: rows paired into 64 x 64-elem rows (128B, full 32 banks),
// then the same 16B-chunk XOR. row in [0,128), k in [0,32).
__device__ __forceinline__ int swp(int row, int k) {
    return sw(row >> 1, (row & 1) * 32 + k);
}

template<int SN>
__global__ __launch_bounds__(256, 4)
void attn_kernel(const float* __restrict__ Qg,
                 const float* __restrict__ Kg,
                 const float* __restrict__ Vg,
                 float* __restrict__ Og,
                 float* __restrict__ Opart,
                 float* __restrict__ lpart)
{
    __shared__ alignas(16) f16_t  Khs[KT * Dh];   // K   [key][d]  fp16 (8 KB)
    __shared__ alignas(16) bf16_t Vts[Dh * KT];   // V^T [d][key]  bf16 (8 KB)
    __shared__ alignas(16) bf16_t Pbs[64 * 64];   // P   row-paired (8 KB)

    const int tid  = threadIdx.x;
    const int lane = tid & 63;
    const int wv   = tid >> 6;       // wave 0..3
    const int l15  = lane & 15;
    const int qd   = lane >> 4;      // quad 0..3
    const int wb   = wv * 32;        // wave's 32-row base in the 128-row tile

    const int bx   = blockIdx.x;
    const int head = bx & 31;                    // XCD grouping
    const int r5   = bx >> 5;
    const int qt   = r5 / SN;                    // 0..15
    const int half = r5 % SN;
    const int tile = head * 16 + qt;             // flat output tile id
    const int ch0  = (SN == 3) ? half * 11 : half * 16;
    const int nch  = (SN == 3) ? (half == 2 ? 10 : 11) : (SN == 2 ? 16 : 32);

    const float* Qp = Qg + (size_t)tile * QT * Dh;
    const float* Kp = Kg + (size_t)head * S * Dh;
    const float* Vp = Vg + (size_t)head * S * Dh;

    // staging address components (constant per thread) — R9 map (coalesced)
    const int skey = tid >> 4;          // K staging: key row
    const int sc4  = (tid & 15) * 4;    // K staging: 4-elem col
    const int vkb  = (tid >> 4) * 4;    // V staging: 4 consecutive keys
    const int vc4  = (tid & 15) * 4;    // V staging: 4 consecutive d

    // ---- Q fragments (B-frag), 2 subtiles x 2 k-steps; log2(e) folded ----
    f16x8 qf[2][2];
    #pragma unroll
    for (int sub = 0; sub < 2; ++sub) {
        const float* qrow = Qp + (size_t)(wb + sub * 16 + l15) * Dh;
        #pragma unroll
        for (int ks = 0; ks < 2; ++ks) {
            const float* p = qrow + ks * 32 + qd * 8;
            const float4 a = *(const float4*)(p);
            const float4 b = *(const float4*)(p + 4);
            const float xs[8] = {a.x, a.y, a.z, a.w, b.x, b.y, b.z, b.w};
            #pragma unroll
            for (int j = 0; j < 8; ++j) qf[sub][ks][j] = (f16_t)(xs[j] * LOG2E);
        }
    }

    f32x4 oa[2][4];      // O acc: [subtile][4 d-tiles of 16]
    float lp[2];         // row-sum partial per subtile (lane's q-row = l15)
    #pragma unroll
    for (int s2 = 0; s2 < 2; ++s2) {
        lp[s2] = 0.f;
        #pragma unroll
        for (int t = 0; t < 4; ++t) oa[s2][t] = (f32x4){0.f, 0.f, 0.f, 0.f};
    }

    // ---- prefetch first chunk into registers ----
    float4 kbuf[4], vbuf[4];
    {
        const float* Kc = Kp + (size_t)ch0 * KT * Dh;
        const float* Vc = Vp + (size_t)ch0 * KT * Dh;
        #pragma unroll
        for (int it = 0; it < 4; ++it)
            kbuf[it] = *(const float4*)(Kc + (size_t)(it * 16 + skey) * Dh + sc4);
        #pragma unroll
        for (int i = 0; i < 4; ++i)
            vbuf[i] = *(const float4*)(Vc + (size_t)(vkb + i) * Dh + vc4);
    }

    #pragma unroll 1
    for (int ci = 0; ci < nch; ++ci) {
        __syncthreads();   // prior iter done reading Khs/Vts

        // ---- write staged registers -> LDS (cvt off the load path) ----
        #pragma unroll
        for (int it = 0; it < 4; ++it) {
            const float xs[4] = {kbuf[it].x, kbuf[it].y, kbuf[it].z, kbuf[it].w};
            union { f16_t h[4]; uint2 u; } ph;
            #pragma unroll
            for (int j = 0; j < 4; ++j) ph.h[j] = (f16_t)xs[j];
            *(uint2*)&Khs[sw(it * 16 + skey, sc4)] = ph.u;
        }
        {
            const float rs[4][4] = {{vbuf[0].x, vbuf[1].x, vbuf[2].x, vbuf[3].x},
                                    {vbuf[0].y, vbuf[1].y, vbuf[2].y, vbuf[3].y},
                                    {vbuf[0].z, vbuf[1].z, vbuf[2].z, vbuf[3].z},
                                    {vbuf[0].w, vbuf[1].w, vbuf[2].w, vbuf[3].w}};
            #pragma unroll
            for (int i = 0; i < 4; ++i) {
                union { bf16_t h[4]; uint2 u; } pv;
                #pragma unroll
                for (int j = 0; j < 4; ++j) pv.h[j] = (bf16_t)rs[i][j];
                *(uint2*)&Vts[sw(vc4 + i, vkb)] = pv.u;
            }
        }
        __syncthreads();

        // ---- issue global loads for next chunk (consumed next iteration) ----
        if (ci + 1 < nch) {
            const float* Kc = Kp + (size_t)(ch0 + ci + 1) * KT * Dh;
            const float* Vc = Vp + (size_t)(ch0 + ci + 1) * KT * Dh;
            #pragma unroll
            for (int it = 0; it < 4; ++it)
                kbuf[it] = *(const float4*)(Kc + (size_t)(it * 16 + skey) * Dh + sc4);
            #pragma unroll
            for (int i = 0; i < 4; ++i)
                vbuf[i] = *(const float4*)(Vc + (size_t)(vkb + i) * Dh + vc4);
        }

        // ---- fused per-np: QK (32 keys) -> exp/P -> PV(ks=np) ----
        #pragma unroll
        for (int np = 0; np < 2; ++np) {
            f32x4 st[2][2];   // [sub][nt within pair]
            #pragma unroll
            for (int s2 = 0; s2 < 2; ++s2)
                #pragma unroll
                for (int t = 0; t < 2; ++t) st[s2][t] = (f32x4){0.f, 0.f, 0.f, 0.f};
            __builtin_amdgcn_s_setprio(1);
            #pragma unroll
            for (int ks = 0; ks < 2; ++ks) {
                const int co = ks * 32 + qd * 8;
                const f16x8 ak0 = *(const f16x8*)&Khs[sw((np * 2 + 0) * 16 + l15, co)];
                const f16x8 ak1 = *(const f16x8*)&Khs[sw((np * 2 + 1) * 16 + l15, co)];
                #pragma unroll
                for (int s2 = 0; s2 < 2; ++s2) {
                    st[s2][0] = __builtin_amdgcn_mfma_f32_16x16x32_f16(ak0, qf[s2][ks], st[s2][0], 0, 0, 0);
                    st[s2][1] = __builtin_amdgcn_mfma_f32_16x16x32_f16(ak1, qf[s2][ks], st[s2][1], 0, 0, 0);
                }
            }
            __builtin_amdgcn_s_setprio(0);
            // p = 2^s; store this np's 32 keys into the 8KB P buffer.
            // Same-wave DS ordering makes the np0-read -> np1-write reuse safe.
            #pragma unroll
            for (int s2 = 0; s2 < 2; ++s2) {
                #pragma unroll
                for (int t = 0; t < 2; ++t) {
                    union { bf16_t h[4]; uint2 u; } pb;
                    #pragma unroll
                    for (int r = 0; r < 4; ++r) {
                        const float e = __builtin_amdgcn_exp2f(st[s2][t][r]);
                        lp[s2] += e;
                        pb.h[r] = (bf16_t)e;
                    }
                    *(uint2*)&Pbs[swp(wb + s2 * 16 + l15, t * 16 + qd * 4)] = pb.u;
                }
            }
            // PV for ks=np (vb shared across subtiles)
            const int co = np * 32 + qd * 8;
            const bf16x8 pa0 = *(const bf16x8*)&Pbs[swp(wb + l15,      qd * 8)];
            const bf16x8 pa1 = *(const bf16x8*)&Pbs[swp(wb + 16 + l15, qd * 8)];
            __builtin_amdgcn_s_setprio(1);
            #pragma unroll
            for (int dt = 0; dt < 4; ++dt) {
                const bf16x8 vb = *(const bf16x8*)&Vts[sw(dt * 16 + l15, co)];
                oa[0][dt] = __builtin_amdgcn_mfma_f32_16x16x32_bf16(pa0, vb, oa[0][dt], 0, 0, 0);
                oa[1][dt] = __builtin_amdgcn_mfma_f32_16x16x32_bf16(pa1, vb, oa[1][dt], 0, 0, 0);
            }
            __builtin_amdgcn_s_setprio(0);
        }
    }

    // ---- reduce row sums (lane's lp covers q-row=l15; reduce across quads) ----
    #pragma unroll
    for (int s2 = 0; s2 < 2; ++s2) {
        lp[s2] += __shfl_xor(lp[s2], 16, 64);
        lp[s2] += __shfl_xor(lp[s2], 32, 64);
    }

    if (SN > 1) {
        float* Po = Opart + (size_t)(tile * SN + half) * (QT * Dh);
        float* lq = lpart + (size_t)(tile * SN + half) * QT;
        #pragma unroll
        for (int s2 = 0; s2 < 2; ++s2) {
            if (qd == 0) lq[wb + s2 * 16 + l15] = lp[s2];
            #pragma unroll
            for (int r = 0; r < 4; ++r) {
                const int row = wb + s2 * 16 + qd * 4 + r;
                #pragma unroll
                for (int dt = 0; dt < 4; ++dt)
                    Po[(size_t)row * Dh + dt * 16 + l15] = oa[s2][dt][r];
            }
        }
    } else {
        float* Op = Og + (size_t)tile * QT * Dh;
        #pragma unroll
        for (int s2 = 0; s2 < 2; ++s2) {
            #pragma unroll
            for (int r = 0; r < 4; ++r) {
                const float inv = 1.0f / __shfl(lp[s2], qd * 4 + r, 64);
                const int row = wb + s2 * 16 + qd * 4 + r;
                #pragma unroll
                for (int dt = 0; dt < 4; ++dt)
                    Op[(size_t)row * Dh + dt * 16 + l15] = oa[s2][dt][r] * inv;
            }
        }
    }
}

// O = sum(Oi) / sum(li); one thread per float4 of output.
template<int SN>
__global__ __launch_bounds__(256)
void combine_kernel(const float* __restrict__ Opart,
                    const float* __restrict__ lpart,
                    float* __restrict__ Og)
{
    const int i  = blockIdx.x * 256 + threadIdx.x;   // float4 index
    const int q  = i >> 11;                          // tile 0..511 (2048 f4/tile)
    const int rw = (i >> 4) & 127;                   // row within tile
    const size_t e = (size_t)(i & 2047) * 4;
    float4 acc = {0.f, 0.f, 0.f, 0.f};
    float  l   = 0.f;
    #pragma unroll
    for (int h = 0; h < SN; ++h) {
        const float4 a = *(const float4*)(Opart + (size_t)(q * SN + h) * (QT * Dh) + e);
        l += lpart[(size_t)(q * SN + h) * QT + rw];
        acc.x += a.x; acc.y += a.y; acc.z += a.z; acc.w += a.w;
    }
    const float inv = 1.0f / l;
    float4 o;
    o.x = acc.x * inv; o.y = acc.y * inv; o.z = acc.z * inv; o.w = acc.w * inv;
    *(float4*)(Og + (size_t)i * 4) = o;
}

extern "C" void kernel_launch(void* const* d_in, const int* in_sizes, int n_in,
                              void* d_out, int out_size, void* d_ws, size_t ws_size,
                              hipStream_t stream)
{
    const float* Q = (const float*)d_in[0];
    const float* K = (const float*)d_in[1];
    const float* V = (const float*)d_in[2];
    float*       O = (float*)d_out;

    constexpr size_t TILE_O = (size_t)QT * Dh;                 // floats per tile
    constexpr size_t NEED3  = (512ull * 3 * (TILE_O + QT)) * sizeof(float); // ~51.1MB
    constexpr size_t NEED2  = (512ull * 2 * (TILE_O + QT)) * sizeof(float); // ~34.1MB
    const int n4 = (int)(512 * TILE_O / 4);                    // output float4 count

    if (ws_size >= NEED3) {
        // 3-way key split: grid 1536 = 6 blocks/CU exactly
        float* Opart = (float*)d_ws;
        float* lpart = Opart + 512ull * 3 * TILE_O;
        attn_kernel<3><<<dim3(1536), dim3(256), 0, stream>>>(
            Q, K, V, nullptr, Opart, lpart);
        combine_kernel<3><<<dim3(n4 / 256), dim3(256), 0, stream>>>(Opart, lpart, O);
    } else if (ws_size >= NEED2) {
        float* Opart = (float*)d_ws;
        float* lpart = Opart + 512ull * 2 * TILE_O;
        attn_kernel<2><<<dim3(1024), dim3(256), 0, stream>>>(
            Q, K, V, nullptr, Opart, lpart);
        combine_kernel<2><<<dim3(n4 / 256), dim3(256), 0, stream>>>(Opart, lpart, O);
    } else {
        attn_kernel<1><<<dim3(512), dim3(256), 0, stream>>>(
            Q, K, V, O, nullptr, nullptr);
    }
}